// Round 11
// baseline (394.724 us; speedup 1.0000x reference)
//
#include <hip/hip_runtime.h>
#include <hip/hip_bf16.h>

#define BB 16
#define CC 384
#define HH 56
#define WW 56
#define PLANE (HH*WW)
#define NHW (BB*PLANE)

typedef __attribute__((ext_vector_type(8)))  short short8;   // 8 bf16 (4 VGPR) MFMA frag
typedef __attribute__((ext_vector_type(16))) float f32x16;   // 32x32 MFMA accumulator
typedef __attribute__((ext_vector_type(4)))  unsigned int uint4v;
typedef __attribute__((ext_vector_type(4)))  float float4v;
typedef unsigned int uint;

// ---------------- Persistent fused kernel: conv(31x31 + 5x5) + BN stats + affine ----------
// Toeplitz-band MFMA conv (R8): per ky out-tile += A x T_ky, K=64 = 4x mfma_32x32x16_bf16.
// Single bf16 band, pair-packed (dword j = w[j-32],w[j-31]) -> ldW 2x ds_read2_b32, no unpack.
// R10 lesson: source ping-pong kept (passed, -5%) but compiler collapses it (VGPR 68).
// R10 diagnosis: the ~116us non-conv residual is INVARIANT across 3 different fuse kernels
//   -> structural (kernel boundary), not code. This version: ONE persistent dispatch.
//   768 blocks = 3/CU x 256 CU EXACTLY resident (46KB LDS, VGPR<=85) -> hand-rolled
//   atomic spin barrier is deadlock-free by capacity arithmetic. NOT cooperative launch
//   (R6: silently no-ops under graph capture). Bounded spin -> visible fail, not hang.
// Each block: band build ONCE; 4 units of {stage 2 planes, conv, pack-store, stats};
//   threadfence -> ctr++ -> spin(ctr==768); BN finalize (atomic stat loads); affine over
//   its OWN 8 planes (own-XCD L2 hot; no cross-block reads -> G16-safe).
// R7 lesson: small-band build biased j-32. R3: epilogue walls + waves_per_eu pin.
// R2 lesson: no compiler unroll of ky loop.
#define PSTR 92                // 184 B row stride: 46 words == 14 mod 32 -> 2-way (free)
#define PROWS 86               // rows -15..70 (15 zero halo each side)
#define PSZ (PROWS*PSTR)       // 7912 shorts per plane
#define WL_W 100               // dwords per large-band ky row, dword j = elems (j-32, j-31)
#define WS_W 80                // dwords per small-band ky row, dword j = elems (j-32, j-31)

static __device__ __forceinline__ short f2bf(float f) {
    unsigned int u = __float_as_uint(f);
    unsigned int r = (u + 0x7fffu + ((u >> 16) & 1u)) >> 16;
    return (short)r;
}

static __device__ __forceinline__ short8 ldA(const short* ap) {
    union { uint u[4]; short8 v; } r;
    uint2 lo = *(const uint2*)(ap);
    uint2 hi = *(const uint2*)(ap + 4);
    r.u[0] = lo.x; r.u[1] = lo.y; r.u[2] = hi.x; r.u[3] = hi.y;
    return r.v;
}

static __device__ __forceinline__ short8 ldW(const uint* p) {
    union { uint u[4]; short8 v; } r;
    r.u[0] = p[0]; r.u[1] = p[2]; r.u[2] = p[4]; r.u[3] = p[6];
    return r.v;
}

__global__ __launch_bounds__(256)
__attribute__((amdgpu_waves_per_eu(3)))
void fused_persist_k(
    const float* __restrict__ x, const float* __restrict__ wL,
    const float* __restrict__ wS, uint* __restrict__ pk,
    float* __restrict__ stats, uint* __restrict__ ctr,
    const float* __restrict__ gL, const float* __restrict__ bL,
    const float* __restrict__ gS, const float* __restrict__ bS,
    float* __restrict__ out)
{
    __shared__ __align__(16) short planes[2*PSZ];   // 31648 B
    __shared__ __align__(16) uint  wpL[31*WL_W];    // 12400 B
    __shared__ __align__(16) uint  wpS[5*WS_W];     //  1600 B
    __shared__ float red_s[16];                     //   -> ~45.7 KB, 3 blk/CU = 768 resident

    const int cp   = blockIdx.x;        // 0..767
    const int c    = cp >> 1;           // channel
    const int half = cp & 1;            // batch half: planes half*8 .. half*8+7
    const int tid  = threadIdx.x;
    const int w    = tid >> 6;
    const int p    = w >> 1;            // plane 0..1 within block
    const int tx   = w & 1;             // column-half this wave owns
    const int lane = tid & 63;
    const int m    = lane & 31;
    const int g    = lane >> 5;

    // ---- zero planes once (halo must stay 0; center fully overwritten per unit) ----
    {
        uint4 z = make_uint4(0,0,0,0);
        uint4* p4 = (uint4*)planes;
        #pragma unroll 1
        for (int i = tid; i < 2*PSZ/8; i += 256) p4[i] = z;
    }

    // ---- band build ONCE per block (amortized over 4 units) ----
    const float* wrow = wL + c*961;
    #pragma unroll 1
    for (int i = tid; i < 31*WL_W; i += 256) {
        int ky = i / WL_W;
        int j  = i - ky*WL_W;
        int widx = j - 32;
        uint lo = (widx   >= 0 && widx   < 31) ? (uint)(unsigned short)f2bf(wrow[ky*31 + widx])     : 0u;
        uint hi = (widx+1 >= 0 && widx+1 < 31) ? (uint)(unsigned short)f2bf(wrow[ky*31 + widx + 1]) : 0u;
        wpL[i] = lo | (hi << 16);
    }
    const float* wrowS = wS + c*25;
    #pragma unroll 1
    for (int i = tid; i < 5*WS_W; i += 256) {
        int ky = i / WS_W;
        int j  = i - ky*WS_W;
        int widx = j - 32;               // read bias toff+31 needs j-32 (R7 lesson)
        uint lo = (widx   >= 0 && widx   < 5) ? (uint)(unsigned short)f2bf(wrowS[ky*5 + widx])     : 0u;
        uint hi = (widx+1 >= 0 && widx+1 < 5) ? (uint)(unsigned short)f2bf(wrowS[ky*5 + widx + 1]) : 0u;
        wpS[i] = lo | (hi << 16);
    }

    // ---- per-lane bases ----
    const int  toff = 8*g - m;
    const uint* wLd = wpL + (toff + 32);       // large: w[k-n]
    const uint* wSd = wpS + (toff + 31);       // small: w2[k-n-1]
    short* pl = planes + p*PSZ;
    const short* abase = pl + m*PSTR + 8*g + tx*24;

    float sL = 0.f, sL2 = 0.f, sS = 0.f, sS2 = 0.f;   // stats across all 4 units

    // ================= phase 1: 4 units of {stage, conv, pack-store} =================
    #pragma unroll 1
    for (int u = 0; u < 4; ++u) {
        const int b = (half*4 + u)*2 + p;      // batch plane for this wave-pair
        __syncthreads();                        // prior unit's LDS reads done (u=0: zero/bands)

        const float4* xp4 = (const float4*)(x + ((size_t)b*CC + c)*PLANE);
        #pragma unroll 1
        for (int i4 = lane + 64*tx; i4 < PLANE/4; i4 += 128) {
            float4 v = xp4[i4];
            int e  = 4*i4;
            int r  = e / WW;                   // 56 % 4 == 0: never crosses rows
            int cc = e - r*WW;
            short* dst = &pl[(r + 15)*PSTR + cc + 15];
            dst[0] = f2bf(v.x); dst[1] = f2bf(v.y); dst[2] = f2bf(v.z); dst[3] = f2bf(v.w);
        }
        __syncthreads();                        // plane visible to pair partner

        f32x16 acc[2] = {};

        // ping-pong pipelined main loop (R10, passed): 31 ky x 4 Ksteps x 2 tiles
        short8 A0[8], B0[4], A1[8], B1[4];
        #pragma unroll
        for (int s = 0; s < 4; ++s) B0[s] = ldW(wLd + 16*s);
        #pragma unroll
        for (int s = 0; s < 4; ++s) {
            A0[2*s]   = ldA(abase + 16*s);
            A0[2*s+1] = ldA(abase + 24*PSTR + 16*s);
        }
        #pragma unroll 1
        for (int ky = 0; ky < 30; ky += 2) {
            {   // prefetch ky+1 -> set1; consume set0 (= ky)
                const uint* wk = wLd + (ky+1)*WL_W;
                const short* ar = abase + (ky+1)*PSTR;
                #pragma unroll
                for (int s = 0; s < 4; ++s) B1[s] = ldW(wk + 16*s);
                #pragma unroll
                for (int s = 0; s < 4; ++s) {
                    A1[2*s]   = ldA(ar + 16*s);
                    A1[2*s+1] = ldA(ar + 24*PSTR + 16*s);
                }
                #pragma unroll
                for (int s = 0; s < 4; ++s) {
                    acc[0] = __builtin_amdgcn_mfma_f32_32x32x16_bf16(A0[2*s],   B0[s], acc[0], 0, 0, 0);
                    acc[1] = __builtin_amdgcn_mfma_f32_32x32x16_bf16(A0[2*s+1], B0[s], acc[1], 0, 0, 0);
                }
            }
            {   // prefetch ky+2 -> set0; consume set1 (= ky+1)
                const uint* wk = wLd + (ky+2)*WL_W;
                const short* ar = abase + (ky+2)*PSTR;
                #pragma unroll
                for (int s = 0; s < 4; ++s) B0[s] = ldW(wk + 16*s);
                #pragma unroll
                for (int s = 0; s < 4; ++s) {
                    A0[2*s]   = ldA(ar + 16*s);
                    A0[2*s+1] = ldA(ar + 24*PSTR + 16*s);
                }
                #pragma unroll
                for (int s = 0; s < 4; ++s) {
                    acc[0] = __builtin_amdgcn_mfma_f32_32x32x16_bf16(A1[2*s],   B1[s], acc[0], 0, 0, 0);
                    acc[1] = __builtin_amdgcn_mfma_f32_32x32x16_bf16(A1[2*s+1], B1[s], acc[1], 0, 0, 0);
                }
            }
        }
        #pragma unroll
        for (int s = 0; s < 4; ++s) {          // tail: ky = 30
            acc[0] = __builtin_amdgcn_mfma_f32_32x32x16_bf16(A0[2*s],   B0[s], acc[0], 0, 0, 0);
            acc[1] = __builtin_amdgcn_mfma_f32_32x32x16_bf16(A0[2*s+1], B0[s], acc[1], 0, 0, 0);
        }

        // epilogue: per tile {5x5 MFMA, masked stats, packed store}
        uint* pout = pk + ((size_t)b*CC + c)*PLANE;
        #pragma unroll
        for (int ty = 0; ty < 2; ++ty) {
            __builtin_amdgcn_sched_barrier(0);
            f32x16 aS_ = {};
            const short* asb = abase + (ty*24 + 13)*PSTR + 12;
            #pragma unroll 1
            for (int k2 = 0; k2 < 5; ++k2) {
                const uint* wk2 = wSd + k2*WS_W;
                const short* ar2 = asb + k2*PSTR;
                #pragma unroll
                for (int s = 0; s < 3; ++s) {
                    short8 bs = ldW(wk2 + 16*s);
                    short8 av = ldA(ar2 + 16*s);
                    aS_ = __builtin_amdgcn_mfma_f32_32x32x16_bf16(av, bs, aS_, 0, 0, 0);
                }
            }
            const float cm = (tx == 0 || m >= 8) ? 1.f : 0.f;
            #pragma unroll
            for (int r = 0; r < 16; ++r) {
                float v  = acc[ty][r];
                float v2 = aS_[r];
                if (ty == 0 || r >= 4) {
                    sL  = fmaf(cm, v,   sL);
                    sL2 = fmaf(cm, v*v, sL2);
                    sS  = fmaf(cm, v2,    sS);
                    sS2 = fmaf(cm, v2*v2, sS2);
                }
                const int row = (r & 3) + 8*(r >> 2) + 4*g;
                const int ofs = (ty*24 + row)*WW + tx*24 + m;
                pout[ofs] = (uint)(unsigned short)f2bf(v) | ((uint)(unsigned short)f2bf(v2) << 16);
            }
        }
    }

    // ---- block reduce stats -> device atomics ----
    #pragma unroll
    for (int off = 32; off > 0; off >>= 1) {
        sL  += __shfl_down(sL,  off);
        sL2 += __shfl_down(sL2, off);
        sS  += __shfl_down(sS,  off);
        sS2 += __shfl_down(sS2, off);
    }
    if (lane == 0) {
        red_s[w*4 + 0] = sL;  red_s[w*4 + 1] = sL2;
        red_s[w*4 + 2] = sS;  red_s[w*4 + 3] = sS2;
    }
    __syncthreads();
    if (tid == 0) {
        float a = 0.f, e = 0.f, d0 = 0.f, e2 = 0.f;
        #pragma unroll
        for (int i = 0; i < 4; ++i) {
            a  += red_s[i*4 + 0]; e  += red_s[i*4 + 1];
            d0 += red_s[i*4 + 2]; e2 += red_s[i*4 + 3];
        }
        atomicAdd(&stats[c],        a);
        atomicAdd(&stats[CC + c],   e);
        atomicAdd(&stats[2*CC + c], d0);
        atomicAdd(&stats[3*CC + c], e2);

        // ---- hand-rolled grid barrier (768 co-resident by capacity arithmetic) ----
        __threadfence();                               // release: stats visible before ctr++
        atomicAdd(ctr, 1u);
        uint spins = 0;
        while (__hip_atomic_load(ctr, __ATOMIC_ACQUIRE, __HIP_MEMORY_SCOPE_AGENT) < (uint)gridDim.x) {
            __builtin_amdgcn_s_sleep(2);
            if (++spins > 100000000u) break;           // visible-fail timeout, never hang
        }
    }
    __syncthreads();

    // ================= phase 2: BN coeffs + affine over own 8 planes =================
    const float inv_n = 1.0f / (float)NHW;
    float s0 = __hip_atomic_load(&stats[c],        __ATOMIC_RELAXED, __HIP_MEMORY_SCOPE_AGENT);
    float s1 = __hip_atomic_load(&stats[CC + c],   __ATOMIC_RELAXED, __HIP_MEMORY_SCOPE_AGENT);
    float s2 = __hip_atomic_load(&stats[2*CC + c], __ATOMIC_RELAXED, __HIP_MEMORY_SCOPE_AGENT);
    float s3 = __hip_atomic_load(&stats[3*CC + c], __ATOMIC_RELAXED, __HIP_MEMORY_SCOPE_AGENT);
    float mL = s0 * inv_n;
    float vL = s1 * inv_n - mL * mL;
    float aL = rsqrtf(vL + 1e-5f) * gL[c];
    float mS = s2 * inv_n;
    float vS = s3 * inv_n - mS * mS;
    float aS = rsqrtf(vS + 1e-5f) * gS[c];
    float cst = bL[c] + bS[c] - mL * aL - mS * aS;

    #define AFF(u) fmaf(aL, __uint_as_float((u) << 16), fmaf(aS, __uint_as_float((u) & 0xffff0000u), cst))
    #define AFF4(dst, src) { float4v t_; t_[0]=AFF(src[0]); t_[1]=AFF(src[1]); t_[2]=AFF(src[2]); t_[3]=AFF(src[3]); dst = t_; }
    #pragma unroll 1
    for (int j = 0; j < 8; ++j) {               // the 8 planes this block wrote (L2-hot)
        const size_t bj = ((size_t)(half*8 + j)*CC + c)*(size_t)PLANE;
        const uint4v* pp = (const uint4v*)(pk + bj);
        float4v*      op = (float4v*)(out + bj);
        uint4v v0 = pp[tid];
        uint4v v1 = pp[tid + 256];
        uint4v v2 = pp[tid + 512];
        float4v r;
        AFF4(r, v0); op[tid]       = r;
        AFF4(r, v1); op[tid + 256] = r;
        AFF4(r, v2); op[tid + 512] = r;
        if (tid < PLANE/4 - 768) {
            uint4v v3 = pp[tid + 768];
            AFF4(r, v3); op[tid + 768] = r;
        }
    }
    #undef AFF4
    #undef AFF
}

// ---------------- Fallback (ws too small): R10 two-kernel path ----------------
template<bool PACK>
__global__ __launch_bounds__(256)
__attribute__((amdgpu_waves_per_eu(3)))
void conv_large_k(
    const float* __restrict__ x, const float* __restrict__ wL,
    const float* __restrict__ wS,
    unsigned short* __restrict__ yL, uint* __restrict__ pk,
    float* __restrict__ stats)
{
    __shared__ __align__(16) short planes[2*PSZ];
    __shared__ __align__(16) uint  wpL[31*WL_W];
    __shared__ __align__(16) uint  wpS[5*WS_W];
    __shared__ float red_s[16];

    const int bid  = blockIdx.x;
    const int c    = bid % CC;
    const int pg   = bid / CC;
    const int tid  = threadIdx.x;
    const int w    = tid >> 6;
    const int p    = w >> 1;
    const int tx   = w & 1;
    const int lane = tid & 63;
    const int m    = lane & 31;
    const int g    = lane >> 5;

    {
        uint4 z = make_uint4(0,0,0,0);
        uint4* p4 = (uint4*)planes;
        #pragma unroll 1
        for (int i = tid; i < 2*PSZ/8; i += 256) p4[i] = z;
    }
    __syncthreads();

    short* pl = planes + p*PSZ;
    const int b = pg*2 + p;
    const float4* xp4 = (const float4*)(x + ((size_t)b*CC + c)*PLANE);
    #pragma unroll 1
    for (int i4 = lane + 64*tx; i4 < PLANE/4; i4 += 128) {
        float4 v = xp4[i4];
        int e  = 4*i4;
        int r  = e / WW;
        int cc = e - r*WW;
        short* dst = &pl[(r + 15)*PSTR + cc + 15];
        dst[0] = f2bf(v.x); dst[1] = f2bf(v.y); dst[2] = f2bf(v.z); dst[3] = f2bf(v.w);
    }

    const float* wrow = wL + c*961;
    #pragma unroll 1
    for (int i = tid; i < 31*WL_W; i += 256) {
        int ky = i / WL_W;
        int j  = i - ky*WL_W;
        int widx = j - 32;
        uint lo = (widx   >= 0 && widx   < 31) ? (uint)(unsigned short)f2bf(wrow[ky*31 + widx])     : 0u;
        uint hi = (widx+1 >= 0 && widx+1 < 31) ? (uint)(unsigned short)f2bf(wrow[ky*31 + widx + 1]) : 0u;
        wpL[i] = lo | (hi << 16);
    }
    const float* wrowS = wS + c*25;
    #pragma unroll 1
    for (int i = tid; i < 5*WS_W; i += 256) {
        int ky = i / WS_W;
        int j  = i - ky*WS_W;
        int widx = j - 32;
        uint lo = (widx   >= 0 && widx   < 5) ? (uint)(unsigned short)f2bf(wrowS[ky*5 + widx])     : 0u;
        uint hi = (widx+1 >= 0 && widx+1 < 5) ? (uint)(unsigned short)f2bf(wrowS[ky*5 + widx + 1]) : 0u;
        wpS[i] = lo | (hi << 16);
    }
    __syncthreads();

    const int  toff = 8*g - m;
    const uint* wLd = wpL + (toff + 32);
    const uint* wSd = wpS + (toff + 31);
    const short* abase = pl + m*PSTR + 8*g + tx*24;

    f32x16 acc[2] = {};

    #pragma unroll 1
    for (int ky = 0; ky < 31; ++ky) {
        const uint* wk = wLd + ky*WL_W;
        short8 Bv[4];
        #pragma unroll
        for (int s = 0; s < 4; ++s) Bv[s] = ldW(wk + 16*s);
        const short* ar = abase + ky*PSTR;
        #pragma unroll
        for (int s = 0; s < 4; ++s) {
            short8 A0 = ldA(ar + 16*s);
            short8 A1 = ldA(ar + 24*PSTR + 16*s);
            acc[0] = __builtin_amdgcn_mfma_f32_32x32x16_bf16(A0, Bv[s], acc[0], 0, 0, 0);
            acc[1] = __builtin_amdgcn_mfma_f32_32x32x16_bf16(A1, Bv[s], acc[1], 0, 0, 0);
        }
    }

    float sL = 0.f, sL2 = 0.f, sS = 0.f, sS2 = 0.f;
    unsigned short* yout = yL + ((size_t)b*CC + c)*PLANE;
    uint*           pout = pk + ((size_t)b*CC + c)*PLANE;

    #pragma unroll
    for (int ty = 0; ty < 2; ++ty) {
        __builtin_amdgcn_sched_barrier(0);
        f32x16 aS_ = {};
        const short* asb = abase + (ty*24 + 13)*PSTR + 12;
        #pragma unroll 1
        for (int k2 = 0; k2 < 5; ++k2) {
            const uint* wk2 = wSd + k2*WS_W;
            const short* ar2 = asb + k2*PSTR;
            #pragma unroll
            for (int s = 0; s < 3; ++s) {
                short8 bs = ldW(wk2 + 16*s);
                short8 av = ldA(ar2 + 16*s);
                aS_ = __builtin_amdgcn_mfma_f32_32x32x16_bf16(av, bs, aS_, 0, 0, 0);
            }
        }
        const float cm = (tx == 0 || m >= 8) ? 1.f : 0.f;
        #pragma unroll
        for (int r = 0; r < 16; ++r) {
            float v  = acc[ty][r];
            float v2 = aS_[r];
            if (ty == 0 || r >= 4) {
                sL  = fmaf(cm, v,   sL);
                sL2 = fmaf(cm, v*v, sL2);
                sS  = fmaf(cm, v2,    sS);
                sS2 = fmaf(cm, v2*v2, sS2);
            }
            const int row = (r & 3) + 8*(r >> 2) + 4*g;
            const int ofs = (ty*24 + row)*WW + tx*24 + m;
            if (PACK) {
                pout[ofs] = (uint)(unsigned short)f2bf(v) | ((uint)(unsigned short)f2bf(v2) << 16);
            } else {
                yout[ofs] = (unsigned short)f2bf(v);
            }
        }
    }

    #pragma unroll
    for (int off = 32; off > 0; off >>= 1) {
        sL  += __shfl_down(sL,  off);
        sL2 += __shfl_down(sL2, off);
        sS  += __shfl_down(sS,  off);
        sS2 += __shfl_down(sS2, off);
    }
    if (lane == 0) {
        red_s[w*4 + 0] = sL;  red_s[w*4 + 1] = sL2;
        red_s[w*4 + 2] = sS;  red_s[w*4 + 3] = sS2;
    }
    __syncthreads();
    if (tid == 0) {
        float a = 0.f, e = 0.f, d0 = 0.f, e2 = 0.f;
        #pragma unroll
        for (int i = 0; i < 4; ++i) {
            a  += red_s[i*4 + 0]; e  += red_s[i*4 + 1];
            d0 += red_s[i*4 + 2]; e2 += red_s[i*4 + 3];
        }
        atomicAdd(&stats[c],        a);
        atomicAdd(&stats[CC + c],   e);
        atomicAdd(&stats[2*CC + c], d0);
        atomicAdd(&stats[3*CC + c], e2);
    }
}

#define ST3 61
__global__ __launch_bounds__(256) void fuse_small_k(
    const float* __restrict__ x, const float* __restrict__ wS,
    const unsigned short* __restrict__ yL, const float* __restrict__ stats,
    const float* __restrict__ gL, const float* __restrict__ bL,
    const float* __restrict__ gS, const float* __restrict__ bS,
    float* __restrict__ out)
{
    __shared__ float in_s[60 * ST3];

    const int bid = blockIdx.x;
    const int c   = bid % CC;
    const int tid = threadIdx.x;
    const float* __restrict__ w2 = wS + c * 25;

    for (int i = tid; i < 60 * ST3; i += 256) in_s[i] = 0.f;
    __syncthreads();

    const float4* xp4 = (const float4*)(x + (size_t)bid * PLANE);
    for (int t = tid; t < PLANE / 4; t += 256) {
        int r  = t / (WW / 4);
        int c4 = (t - r * (WW / 4)) * 4;
        float4 v = xp4[t];
        float* dst = &in_s[(r + 2) * ST3 + 2 + c4];
        dst[0] = v.x; dst[1] = v.y; dst[2] = v.z; dst[3] = v.w;
    }
    __syncthreads();

    const float inv_n = 1.0f / (float)NHW;
    float mL = stats[c]          * inv_n;
    float vL = stats[CC + c]     * inv_n - mL * mL;
    float aL = rsqrtf(vL + 1e-5f) * gL[c];
    float mS = stats[2*CC + c]   * inv_n;
    float vS = stats[3*CC + c]   * inv_n - mS * mS;
    float aS = rsqrtf(vS + 1e-5f) * gS[c];
    float cst = bL[c] + bS[c] - mL * aL - mS * aS;

    const unsigned short* yp = yL + (size_t)bid * PLANE;
    float* op = out + (size_t)bid * PLANE;

    #pragma unroll 1
    for (int t = tid; t < PLANE / 4; t += 256) {
        int r  = t / 14;
        int c4 = (t - r * 14) * 4;
        float o0 = 0.f, o1 = 0.f, o2 = 0.f, o3 = 0.f;
        #pragma unroll
        for (int ky = 0; ky < 5; ++ky) {
            const float* rp = &in_s[(r + ky) * ST3 + c4];
            float f[9];
            #pragma unroll
            for (int j = 0; j < 9; ++j) f[j] = rp[j];
            const float* wr = w2 + ky * 5;
            #pragma unroll
            for (int kx = 0; kx < 5; ++kx) {
                float wv = wr[kx];
                o0 = fmaf(f[kx + 0], wv, o0);
                o1 = fmaf(f[kx + 1], wv, o1);
                o2 = fmaf(f[kx + 2], wv, o2);
                o3 = fmaf(f[kx + 3], wv, o3);
            }
        }
        ushort4 yv = *(const ushort4*)(yp + 4 * t);
        float4 res;
        res.x = fmaf(aL, __uint_as_float(((uint)yv.x) << 16), fmaf(aS, o0, cst));
        res.y = fmaf(aL, __uint_as_float(((uint)yv.y) << 16), fmaf(aS, o1, cst));
        res.z = fmaf(aL, __uint_as_float(((uint)yv.z) << 16), fmaf(aS, o2, cst));
        res.w = fmaf(aL, __uint_as_float(((uint)yv.w) << 16), fmaf(aS, o3, cst));
        *(float4*)(op + 4 * t) = res;
    }
}

extern "C" void kernel_launch(void* const* d_in, const int* in_sizes, int n_in,
                              void* d_out, int out_size, void* d_ws, size_t ws_size,
                              hipStream_t stream) {
    const float* x  = (const float*)d_in[0];
    const float* wL = (const float*)d_in[1];
    const float* gL = (const float*)d_in[2];
    const float* bL = (const float*)d_in[3];
    const float* wS = (const float*)d_in[4];
    const float* gS = (const float*)d_in[5];
    const float* bS = (const float*)d_in[6];
    float* out = (float*)d_out;

    const size_t pk_bytes = (size_t)BB * CC * PLANE * sizeof(uint);           // 77 MB
    const size_t yl_bytes = (size_t)BB * CC * PLANE * sizeof(unsigned short); // 38.5 MB
    const bool pack = ws_size >= pk_bytes + 4 * CC * sizeof(float) + 16;

    if (pack) {
        uint* pkbuf  = (uint*)d_ws;
        float* stats = (float*)((char*)d_ws + pk_bytes);
        uint*  ctr   = (uint*)(stats + 4 * CC);
        hipMemsetAsync(stats, 0, 4 * CC * sizeof(float) + 16, stream);  // stats + barrier ctr
        fused_persist_k<<<2 * CC, 256, 0, stream>>>(x, wL, wS, pkbuf, stats, ctr,
                                                    gL, bL, gS, bS, out);
    } else {
        unsigned short* yLbuf = (unsigned short*)d_ws;
        float* stats = (float*)((char*)d_ws + yl_bytes);
        hipMemsetAsync(stats, 0, 4 * CC * sizeof(float), stream);
        conv_large_k<false><<<8 * CC, 256, 0, stream>>>(x, wL, wS, yLbuf, (uint*)d_ws, stats);
        fuse_small_k<<<BB * CC, 256, 0, stream>>>(x, wS, yLbuf, stats, gL, bL, gS, bS, out);
    }
}